// Round 7
// baseline (39.241 us; speedup 1.0000x reference)
//
#include <hip/hip_runtime.h>
#include <math.h>

namespace {

constexpr int kB = 4;
constexpr int kS = 4;
constexpr int kM = 1024;
constexpr int kN = 8192;
constexpr int kBS = kB * kS;
constexpr float kBig2 = 1e20f;  // sqrt(1e20) = 1e10 == reference BIG

constexpr int NSPL1 = 16;                        // K1: gt split, tiles of 128
constexpr int K1_TILE = 128;
constexpr int K1_BLOCKS = kBS * NSPL1;           // 256
constexpr int GSPL = 2;                          // K2: gt chunks of 1024
constexpr int MSPL = 8;                          // K2: pred tiles of 128
constexpr int K2_BLOCKS = kBS * GSPL * MSPL;     // 256

constexpr int NCHUNK = 32;                       // scatter chunks (1024 pts, 8/b)

// ---- workspace layout (4-byte words); all plain-store, no init needed ----
constexpr int OFF_PD1 = 0;                               // [NSPL1][kBS*kM] partial mins
constexpr int OFF_PDM = OFF_PD1 + NSPL1 * kBS * kM;      // [MSPL][kBS*kN] partial mins
constexpr int OFF_C4 = OFF_PDM + MSPL * kBS * kN;        // float4[kBS*kN] gt {x,y,z,|g|^2}
constexpr int OFF_P4 = OFF_C4 + 4 * kBS * kN;            // float4[kBS*kM] pred {x,y,z,|p|^2}
constexpr int OFF_HIST = OFF_P4 + 4 * kBS * kM;          // [NCHUNK][kS] chunk histograms
constexpr int OFF_CNT = OFF_HIST + NCHUNK * kS;          // [kBS] bucket counts

constexpr int P4_BLOCKS = kBS * kM / 256;        // 64

// phase A: per-chunk label histograms (ballot-counted), pred float4 build, out=0.
__global__ __launch_bounds__(256) void kprepA(const float* __restrict__ ret,
                                              const float4* __restrict__ gt,
                                              unsigned int* __restrict__ ws,
                                              float* __restrict__ out) {
  const int blk = blockIdx.x, tid = threadIdx.x;
  if (blk < NCHUNK) {
    const int wave = tid >> 6, lane = tid & 63;
    int c0 = 0, c1 = 0, c2 = 0, c3 = 0;
#pragma unroll
    for (int r = 0; r < 4; ++r) {
      const int s = (int)gt[blk * 1024 + r * 256 + tid].w;
      const unsigned long long m0 = __ballot(s == 0);
      const unsigned long long m1 = __ballot(s == 1);
      const unsigned long long m2 = __ballot(s == 2);
      const unsigned long long m3 = __ballot(s == 3);
      if (lane == 0) {
        c0 += (int)__popcll(m0); c1 += (int)__popcll(m1);
        c2 += (int)__popcll(m2); c3 += (int)__popcll(m3);
      }
    }
    __shared__ int wc[4][kS];
    if (lane == 0) { wc[wave][0] = c0; wc[wave][1] = c1; wc[wave][2] = c2; wc[wave][3] = c3; }
    __syncthreads();
    if (tid < kS)
      ((int*)ws)[OFF_HIST + blk * kS + tid] = wc[0][tid] + wc[1][tid] + wc[2][tid] + wc[3][tid];
    if (blk == 0 && tid == 64) out[0] = 0.f;
    return;
  }
  const int gi = (blk - NCHUNK) * 256 + tid;
  const float x = ret[gi * 3], y = ret[gi * 3 + 1], z = ret[gi * 3 + 2];
  ((float4*)(ws + OFF_P4))[gi] = make_float4(x, y, z, fmaf(x, x, fmaf(y, y, z * z)));
}

// phase B: deterministic scatter — chunk base from histogram prefix, LDS cursors,
// zero global atomics. Last chunk of each b writes final bucket counts.
__global__ __launch_bounds__(256) void kscatter(const float4* __restrict__ gt,
                                                unsigned int* __restrict__ ws) {
  const int c = blockIdx.x, tid = threadIdx.x;
  const int b = c >> 3, cloc = c & 7;
  const int wave = tid >> 6, lane = tid & 63;
  __shared__ int hist[8][kS];    // all 8 chunks of this b
  __shared__ int cursor[kS];     // running relative offset within bucket
  __shared__ int wcnt[4][kS];    // per-wave counts, current round
  if (tid < 32) hist[tid >> 2][tid & 3] = ((const int*)ws)[OFF_HIST + (b * 8) * kS + tid];
  __syncthreads();
  if (tid < kS) {
    int base = 0;
    for (int cc = 0; cc < cloc; ++cc) base += hist[cc][tid];
    cursor[tid] = base;
  }
  float4* c4 = (float4*)(ws + OFF_C4);
#pragma unroll
  for (int r = 0; r < 4; ++r) {
    __syncthreads();
    const float4 q = gt[c * 1024 + r * 256 + tid];
    const int s = (int)q.w;
    int rank = 0;
#pragma unroll
    for (int ss = 0; ss < kS; ++ss) {
      const unsigned long long m = __ballot(s == ss);
      if (lane == 0) wcnt[wave][ss] = (int)__popcll(m);
      if (s == ss) rank = (int)__popcll(m & ((1ull << lane) - 1ull));
    }
    __syncthreads();
    int pos = cursor[s] + rank;
#pragma unroll
    for (int w = 0; w < 4; ++w)
      if (w < wave) pos += wcnt[w][s];
    const float gn = fmaf(q.x, q.x, fmaf(q.y, q.y, q.z * q.z));
    c4[(b * kS + s) * kN + pos] = make_float4(q.x, q.y, q.z, gn);
    __syncthreads();
    if (tid < kS) cursor[tid] += wcnt[0][tid] + wcnt[1][tid] + wcnt[2][tid] + wcnt[3][tid];
  }
  __syncthreads();
  if (cloc == 7 && tid < kS) ((int*)ws)[OFF_CNT + b * kS + tid] = cursor[tid];
}

// dist, dot-expansion (3 FMA + 1 min per pair), atomic-free partial-plane stores.
__global__ __launch_bounds__(256) void kdist(unsigned int* __restrict__ ws) {
  const int tid = threadIdx.x;
  __shared__ float4 tile[K1_TILE];
  const int* cnt_p = (const int*)ws + OFF_CNT;
  const float4* c4 = (const float4*)(ws + OFF_C4);
  const float4* p4 = (const float4*)(ws + OFF_P4);
  float* pd1 = (float*)(ws + OFF_PD1);
  float* pdm = (float*)(ws + OFF_PDM);

  if (blockIdx.x < K1_BLOCKS) {
    const int t = blockIdx.x & (NSPL1 - 1);
    const int bs = blockIdx.x >> 4;
    const int cnt = cnt_p[bs];
    const float4 P0 = p4[bs * kM + tid];
    const float4 P1 = p4[bs * kM + tid + 256];
    const float4 P2 = p4[bs * kM + tid + 512];
    const float4 P3 = p4[bs * kM + tid + 768];
    const float ax0 = -2.f * P0.x, ay0 = -2.f * P0.y, az0 = -2.f * P0.z;
    const float ax1 = -2.f * P1.x, ay1 = -2.f * P1.y, az1 = -2.f * P1.z;
    const float ax2 = -2.f * P2.x, ay2 = -2.f * P2.y, az2 = -2.f * P2.z;
    const float ax3 = -2.f * P3.x, ay3 = -2.f * P3.y, az3 = -2.f * P3.z;
    float b0 = kBig2, b1 = kBig2, b2 = kBig2, b3 = kBig2;
    for (int start = t * K1_TILE; start < cnt; start += NSPL1 * K1_TILE) {
      __syncthreads();
      if (tid < K1_TILE) {
        const int j = start + tid;
        tile[tid] = (j < cnt) ? c4[bs * kN + j] : make_float4(0.f, 0.f, 0.f, kBig2);
      }
      __syncthreads();
#pragma unroll 8
      for (int j = 0; j < K1_TILE; ++j) {
        const float4 g = tile[j];  // wave-uniform -> LDS broadcast
        b0 = fminf(b0, fmaf(ax0, g.x, fmaf(ay0, g.y, fmaf(az0, g.z, g.w))));
        b1 = fminf(b1, fmaf(ax1, g.x, fmaf(ay1, g.y, fmaf(az1, g.z, g.w))));
        b2 = fminf(b2, fmaf(ax2, g.x, fmaf(ay2, g.y, fmaf(az2, g.z, g.w))));
        b3 = fminf(b3, fmaf(ax3, g.x, fmaf(ay3, g.y, fmaf(az3, g.z, g.w))));
      }
    }
    // one writer per (t, bs, m) slot — plain stores, |p|^2 added outside the min.
    float* row = pd1 + t * (kBS * kM) + bs * kM + tid;
    row[0] = b0 + P0.w;
    row[256] = b1 + P1.w;
    row[512] = b2 + P2.w;
    row[768] = b3 + P3.w;
  } else {
    int r = blockIdx.x - K1_BLOCKS;
    const int ms = r & (MSPL - 1); r >>= 3;
    const int gs = r & (GSPL - 1); r >>= 1;
    const int bs = r;
    const int cnt = cnt_p[bs];
    if (tid < K1_TILE) tile[tid] = p4[bs * kM + ms * K1_TILE + tid];
    __syncthreads();
    float* plane = pdm + ms * (kBS * kN) + bs * kN;
    for (int base = gs * 1024; base < cnt; base += GSPL * 1024) {
      const int l0 = base + tid, l1 = l0 + 256, l2 = l0 + 512, l3 = l0 + 768;
      const bool v0 = l0 < cnt, v1 = l1 < cnt, v2 = l2 < cnt, v3 = l3 < cnt;
      const float4 G0 = v0 ? c4[bs * kN + l0] : make_float4(0.f, 0.f, 0.f, 0.f);
      const float4 G1 = v1 ? c4[bs * kN + l1] : make_float4(0.f, 0.f, 0.f, 0.f);
      const float4 G2 = v2 ? c4[bs * kN + l2] : make_float4(0.f, 0.f, 0.f, 0.f);
      const float4 G3 = v3 ? c4[bs * kN + l3] : make_float4(0.f, 0.f, 0.f, 0.f);
      const float ax0 = -2.f * G0.x, ay0 = -2.f * G0.y, az0 = -2.f * G0.z;
      const float ax1 = -2.f * G1.x, ay1 = -2.f * G1.y, az1 = -2.f * G1.z;
      const float ax2 = -2.f * G2.x, ay2 = -2.f * G2.y, az2 = -2.f * G2.z;
      const float ax3 = -2.f * G3.x, ay3 = -2.f * G3.y, az3 = -2.f * G3.z;
      float b0 = kBig2, b1 = kBig2, b2 = kBig2, b3 = kBig2;
#pragma unroll 8
      for (int mm = 0; mm < K1_TILE; ++mm) {
        const float4 p = tile[mm];  // wave-uniform broadcast
        b0 = fminf(b0, fmaf(ax0, p.x, fmaf(ay0, p.y, fmaf(az0, p.z, p.w))));
        b1 = fminf(b1, fmaf(ax1, p.x, fmaf(ay1, p.y, fmaf(az1, p.z, p.w))));
        b2 = fminf(b2, fmaf(ax2, p.x, fmaf(ay2, p.y, fmaf(az2, p.z, p.w))));
        b3 = fminf(b3, fmaf(ax3, p.x, fmaf(ay3, p.y, fmaf(az3, p.z, p.w))));
      }
      // one writer per (ms, bs, i) slot — plain stores.
      if (v0) plane[l0] = b0 + G0.w;
      if (v1) plane[l1] = b1 + G1.w;
      if (v2) plane[l2] = b2 + G2.w;
      if (v3) plane[l3] = b3 + G3.w;
    }
  }
}

// epilogue: one block per (b,s); min over partial planes, sqrt-mean both
// directions, chamfer, atomicAdd into out (out zeroed by kprepA).
__global__ __launch_bounds__(256) void krf(const unsigned int* __restrict__ ws,
                                           float* __restrict__ out) {
  const int tid = threadIdx.x, lane = tid & 63, wid = tid >> 6;
  const int bs = blockIdx.x, b = bs >> 2;
  const int* cnt_p = (const int*)ws + OFF_CNT;
  const int cnt = cnt_p[bs];
  const float* pd1 = (const float*)(ws + OFF_PD1) + bs * kM;
  const float* pdm = (const float*)(ws + OFF_PDM) + bs * kN;
  float s1 = 0.f;
  for (int m = tid; m < kM; m += 256) {
    float u = pd1[m];
#pragma unroll
    for (int t = 1; t < NSPL1; ++t) u = fminf(u, pd1[t * (kBS * kM) + m]);
    s1 += sqrtf(fmaxf(u, 1e-12f));
  }
  float s2 = 0.f;
  for (int i = tid; i < cnt; i += 256) {
    float u = pdm[i];
#pragma unroll
    for (int t = 1; t < MSPL; ++t) u = fminf(u, pdm[t * (kBS * kN) + i]);
    s2 += sqrtf(fmaxf(u, 1e-12f));
  }
  for (int o = 32; o > 0; o >>= 1) {
    s1 += __shfl_down(s1, o);
    s2 += __shfl_down(s2, o);
  }
  __shared__ float r1[4], r2[4];
  if (lane == 0) { r1[wid] = s1; r2[wid] = s2; }
  __syncthreads();
  if (tid == 0) {
    const float a1 = r1[0] + r1[1] + r1[2] + r1[3];
    const float a2 = r2[0] + r2[1] + r2[2] + r2[3];
    int pres = 0;
    for (int s = 0; s < kS; ++s) pres += cnt_p[b * kS + s] > 0 ? 1 : 0;
    const float cham = cnt > 0 ? 0.5f * (a1 / (float)kM + a2 / (float)max(cnt, 1)) : 0.f;
    atomicAdd(out, cham / (float)(kB * max(pres, 1)));
  }
}

}  // namespace

extern "C" void kernel_launch(void* const* d_in, const int* in_sizes, int n_in,
                              void* d_out, int out_size, void* d_ws, size_t ws_size,
                              hipStream_t stream) {
  const float* ret = (const float*)d_in[0];    // (B, S*M*3) f32 == (BS, M, 3)
  const float4* gt = (const float4*)d_in[1];   // (B, N, 4) f32
  unsigned int* ws = (unsigned int*)d_ws;
  float* out = (float*)d_out;

  kprepA<<<NCHUNK + P4_BLOCKS, 256, 0, stream>>>(ret, gt, ws, out);
  kscatter<<<NCHUNK, 256, 0, stream>>>(gt, ws);
  kdist<<<K1_BLOCKS + K2_BLOCKS, 256, 0, stream>>>(ws);
  krf<<<kBS, 256, 0, stream>>>(ws, out);
}